// Round 11
// baseline (223.169 us; speedup 1.0000x reference)
//
#include <hip/hip_runtime.h>
#include <stdint.h>

// DetectionBaseline: SSD post-process. R11 (on R10's fused structure):
//  - sort uses 4 waves x 8 regs (R4-verified layout): LDS rounds 6 -> 3 (12 -> 6 barriers)
//  - P2 (kill-row build for chunk c+1) runs on waves 1-7 DURING wave-0's P3 resolve of
//    chunk c (double-buffered srow): 2 barriers/chunk instead of 3, P2 off critical path
//   prep      : per (b,a) box decode + softmax (m,sum)   [batch-shared]
//   fused_nms : per (b,c): key build -> sort -> pipelined chunked greedy NMS
//   merge     : per b truncated pairwise bitonic merges -> top-200 output

#define A_N     1280
#define CF      20
#define NC      21
#define B_N     16
#define TOPK    200
#define THREADS 256
#define CTHREADS 512
#define SORT_N  2048
#define CH      128

// ws layout (bytes)
#define KEYS_BYTES   (B_N * CF * TOPK * 8)                 // 512000 kept-key lists
#define BOX_OFF      KEYS_BYTES                             // float4 [16*1280] = 327680
#define MS_OFF       (BOX_OFF + B_N * A_N * 16)             // float2 [16*1280] = 163840
#define WS_B_BYTES   (MS_OFF + B_N * A_N * 8)               // 1003520 (fused tier)

#define F4INV make_float4(-8.f, -8.f, -8.f, -8.f)

static __device__ __forceinline__ uint64_t pack_key(float sc, uint32_t idx) {
    // softmax scores positive -> float bits monotone. ~bits => ascending key = descending
    // score; low 32 bits = index => ties break toward smaller index (stable argsort / top_k).
    return ((uint64_t)(uint32_t)(~__float_as_uint(sc)) << 32) | (uint64_t)idx;
}

static __device__ __forceinline__ float box_area(const float4 v) {
    return (v.z - v.x) * (v.w - v.y);
}

static __device__ __forceinline__ bool iou_gt(const float4 a, const float aarea,
                                              const float4 b, const float barea) {
    // ref-exact: inter/(area_a + area_b - inter) > 0.45; exactly symmetric in IEEE
    const float lx = fmaxf(a.x, b.x);
    const float ly = fmaxf(a.y, b.y);
    const float rx = fminf(a.z, b.z);
    const float ry = fminf(a.w, b.w);
    const float wx = fmaxf(rx - lx, 0.0f);
    const float wy = fmaxf(ry - ly, 0.0f);
    const float inter = wx * wy;
    const float uni   = aarea + barea - inter;
    return inter / uni > 0.45f;
}

static __device__ __forceinline__ float4 decode_box(const float4 lc, const float4 an) {
    const float cx = lc.x * an.z / 10.0f + an.x;
    const float cy = lc.y * an.w / 10.0f + an.y;
    const float w  = expf(lc.z / 5.0f) * an.z;
    const float h  = expf(lc.w / 5.0f) * an.w;
    float4 v;
    v.x = cx - w / 2.0f; v.y = cy - h / 2.0f;
    v.z = cx + w / 2.0f; v.w = cy + h / 2.0f;
    return v;
}

static __device__ __forceinline__ float4 shfl_box(const float4 v, int lane) {
    float4 r;
    r.x = __shfl(v.x, lane, 64);
    r.y = __shfl(v.y, lane, 64);
    r.z = __shfl(v.z, lane, 64);
    r.w = __shfl(v.w, lane, 64);
    return r;
}

static __device__ __forceinline__ uint64_t readlane_u64(uint64_t v, int lane) {
    const uint32_t lo = (uint32_t)__builtin_amdgcn_readlane((int)(uint32_t)v, lane);
    const uint32_t hi = (uint32_t)__builtin_amdgcn_readlane((int)(uint32_t)(v >> 32), lane);
    return ((uint64_t)hi << 32) | lo;
}

// ---- prep: per (b,a) decoded box + softmax (max, sum) ----
__global__ __launch_bounds__(THREADS)
void prep_kernel(const float* __restrict__ locs,
                 const float* __restrict__ scores,
                 const float* __restrict__ anchors,
                 float4* __restrict__ boxes_ws,
                 float2* __restrict__ ms_ws)
{
    const int g = blockIdx.x * THREADS + threadIdx.x;
    if (g >= B_N * A_N) return;
    const int a = g % A_N;
    boxes_ws[g] = decode_box(((const float4*)locs)[g], ((const float4*)anchors)[a]);
    const float* sp = scores + (size_t)g * NC;
    float m = sp[0];
    #pragma unroll
    for (int k = 1; k < NC; ++k) m = fmaxf(m, sp[k]);
    float sum = 0.0f;
    #pragma unroll
    for (int k = 0; k < NC; ++k) sum += expf(sp[k] - m);
    ms_ws[g] = make_float2(m, sum);
}

// ---- fused_nms (512 threads): key build + 4-wave sort + pipelined chunked NMS ----
__global__ __launch_bounds__(CTHREADS)
void fused_nms_kernel(const float* __restrict__ scores,
                      const float2* __restrict__ ms_ws,
                      const float4* __restrict__ boxes_ws,
                      uint64_t* __restrict__ ws_keys)
{
    __shared__ uint64_t      skeys[SORT_N];      // 16 KB sorted keys
    __shared__ uint64_t      srowbuf[2][CH][2];  // double-buffered kill rows (4 KB)
    __shared__ unsigned char sdead[CH];
    __shared__ float4        swbox[TOPK];        // winner boxes (cross-test)
    __shared__ float         swarea[TOPK];       // winner areas
    __shared__ uint64_t      swkey[TOPK];        // winner sorted keys (rank order)
    __shared__ int           sW;

    const int blk = blockIdx.x;
    const int b   = blk / CF;
    const int c   = blk % CF + 1;             // class channel 1..20
    const int t   = threadIdx.x;              // 0..511
    const int l   = t & 63;
    const int w   = t >> 6;                   // 0..7

    // ---- key build (ref-exact softmax from prep's m,sum) ----
    #pragma unroll
    for (int i = 0; i < SORT_N / CTHREADS; ++i) {
        const int a = t + i * CTHREADS;
        if (a < A_N) {
            const float2 ms = ms_ws[b * A_N + a];
            const float  sl = scores[((size_t)b * A_N + a) * NC + c];
            const float  sc = expf(sl - ms.x) / ms.y;
            skeys[a] = (sc > 0.01f) ? pack_key(sc, (uint32_t)a) : ~0ull;
        } else {
            skeys[a] = ~0ull;
        }
    }
    if (t == 0) sW = 0;
    __syncthreads();

    // ---- register/wave bitonic sort: waves 0-3, 8 keys/thread, e=(w<<9)|(r<<6)|l
    //      (R4-verified layout: j in {64,128,256} in-register -> only 3 LDS rounds) ----
    const bool sorter = (w < 4);
    uint64_t k[8];
    if (sorter) {
        #pragma unroll
        for (int r = 0; r < 8; ++r) k[r] = skeys[(w << 9) + (r << 6) + l];
    }
    for (int kk = 2; kk <= SORT_N; kk <<= 1) {
        for (int j = kk >> 1; j; j >>= 1) {       // uniform loop -> barriers uniform
            if (j >= 512) {
                __syncthreads();
                if (sorter) {
                    #pragma unroll
                    for (int r = 0; r < 8; ++r) skeys[(w << 9) + (r << 6) + l] = k[r];
                }
                __syncthreads();
                if (sorter) {
                    #pragma unroll
                    for (int r = 0; r < 8; ++r) {
                        const int e = (w << 9) + (r << 6) + l;
                        const uint64_t o = skeys[e ^ j];
                        const bool keep_min = (((e & j) == 0) == ((e & kk) == 0));
                        const uint64_t mn = k[r] < o ? k[r] : o;
                        const uint64_t mx = k[r] < o ? o : k[r];
                        k[r] = keep_min ? mn : mx;
                    }
                }
            } else if (j >= 64) {
                if (sorter) {
                    const int rb = j >> 6;            // 1, 2, or 4
                    #pragma unroll
                    for (int r = 0; r < 8; ++r) {
                        if ((r & rb) == 0) {
                            const int p = r | rb;
                            const int e = (w << 9) + (r << 6) + l;
                            const bool up = ((e & kk) == 0);
                            const uint64_t x = k[r], y = k[p];
                            const uint64_t mn = x < y ? x : y;
                            const uint64_t mx = x < y ? y : x;
                            k[r] = up ? mn : mx;
                            k[p] = up ? mx : mn;
                        }
                    }
                }
            } else {
                if (sorter) {
                    #pragma unroll
                    for (int r = 0; r < 8; ++r) {
                        const uint64_t o = (uint64_t)__shfl_xor((unsigned long long)k[r], j, 64);
                        const int e = (w << 9) + (r << 6) + l;
                        const bool keep_min = (((e & j) == 0) == ((e & kk) == 0));
                        const uint64_t mn = k[r] < o ? k[r] : o;
                        const uint64_t mx = k[r] < o ? o : k[r];
                        k[r] = keep_min ? mn : mx;
                    }
                }
            }
        }
    }
    __syncthreads();   // last LDS-pass readers done before overwrite
    if (sorter) {
        #pragma unroll
        for (int r = 0; r < 8; ++r) skeys[(w << 9) + (r << 6) + l] = k[r];
    }
    __syncthreads();

    // ---- chunk-loop prologue: build rows + sdead for chunk 0 (no winners yet) ----
    const float4* const bbase = boxes_ws + (size_t)b * A_N;
    {
        const uint64_t k0 = skeys[l];
        const uint64_t k1 = skeys[64 + l];
        const float4 b_lo = (k0 != ~0ull) ? bbase[(uint32_t)k0] : F4INV;
        const float4 b_hi = (k1 != ~0ull) ? bbase[(uint32_t)k1] : F4INV;
        const float a_lo = box_area(b_lo), a_hi = box_area(b_hi);
        const int rb0 = w * 16;                    // all 8 waves, 16 rows each
        for (int row = rb0; row < rb0 + 16; ++row) {
            const float4 rbx = shfl_box(row < 64 ? b_lo : b_hi, row & 63);
            const float  ra  = box_area(rbx);
            const uint64_t m0 = __ballot(iou_gt(rbx, ra, b_lo, a_lo));
            const uint64_t m1 = __ballot(iou_gt(rbx, ra, b_hi, a_hi));
            if (l == 0) { srowbuf[0][row][0] = m0; srowbuf[0][row][1] = m1; }
        }
    }
    for (int i = t; i < CH; i += CTHREADS) sdead[i] = (skeys[i] == ~0ull) ? 1 : 0;
    __syncthreads();

    // ---- pipelined chunked greedy NMS: 2 barriers/chunk, P2 hidden under P3 ----
    int W = 0, cur = 0;
    for (int cb = 0; cb < A_N; cb += CH) {
        if (skeys[cb] == ~0ull) break;        // sorted: rest invalid (uniform)

        // Phase A: wave 0 resolves chunk cb; waves 1-7 build next chunk's kill rows
        if (w == 0) {
            const uint64_t key0 = skeys[cb + l];
            const uint64_t key1 = skeys[cb + 64 + l];
            const bool v0 = (key0 != ~0ull), v1 = (key1 != ~0ull);
            const float4 box_lo = v0 ? bbase[(uint32_t)key0] : F4INV;
            const float4 box_hi = v1 ? bbase[(uint32_t)key1] : F4INV;
            const float  al = box_area(box_lo);
            const float  ah = box_area(box_hi);
            const uint64_t r0lo = srowbuf[cur][l][0];        // row l
            const uint64_t r0hi = srowbuf[cur][l][1];
            const uint64_t r1lo = srowbuf[cur][64 + l][0];   // row 64+l
            const uint64_t r1hi = srowbuf[cur][64 + l][1];
            uint64_t alive0 = __ballot(sdead[l] == 0);
            uint64_t alive1 = __ballot(sdead[64 + l] == 0);
            int Wl = W;
            while ((alive0 | alive1) && Wl < TOPK) {
                const int f = alive0 ? __builtin_ctzll(alive0)
                                     : 64 + __builtin_ctzll(alive1);
                if (f < 64) {
                    if (l == f)      { swkey[Wl] = key0; swbox[Wl] = box_lo; swarea[Wl] = al; }
                } else {
                    if (l == f - 64) { swkey[Wl] = key1; swbox[Wl] = box_hi; swarea[Wl] = ah; }
                }
                uint64_t klo, khi;
                if (f < 64) { klo = readlane_u64(r0lo, f);      khi = readlane_u64(r0hi, f); }
                else        { klo = readlane_u64(r1lo, f - 64); khi = readlane_u64(r1hi, f - 64); }
                alive0 &= ~klo;                  // winner self-clears (diag IoU = 1)
                alive1 &= ~khi;
                ++Wl;
            }
            if (l == 0) sW = Wl;
        } else if (cb + CH < A_N) {
            // build kill rows of chunk cb+CH (sort-only dependence -> overlaps P3)
            const int cbn = cb + CH;
            const uint64_t nk0 = skeys[cbn + l];
            const uint64_t nk1 = skeys[cbn + 64 + l];
            const float4 nb_lo = (nk0 != ~0ull) ? bbase[(uint32_t)nk0] : F4INV;
            const float4 nb_hi = (nk1 != ~0ull) ? bbase[(uint32_t)nk1] : F4INV;
            const float  nal = box_area(nb_lo), nah = box_area(nb_hi);
            const int rb0 = (w - 1) * 19;               // 7 waves cover 128 rows
            const int rb1 = (rb0 + 19 < CH) ? rb0 + 19 : CH;
            for (int row = rb0; row < rb1; ++row) {
                const float4 rbx = shfl_box(row < 64 ? nb_lo : nb_hi, row & 63);
                const float  ra  = box_area(rbx);
                const uint64_t m0 = __ballot(iou_gt(rbx, ra, nb_lo, nal));
                const uint64_t m1 = __ballot(iou_gt(rbx, ra, nb_hi, nah));
                if (l == 0) { srowbuf[cur ^ 1][row][0] = m0; srowbuf[cur ^ 1][row][1] = m1; }
            }
        }
        __syncthreads();
        W = sW;
        if (W >= TOPK) break;

        // Phase B: cross-test next chunk's boxes vs all winners so far -> sdead
        if (cb + CH < A_N) {
            const int cbn = cb + CH;
            const int bx = t >> 2, q = t & 3;            // 4 helpers per box
            const uint64_t keyx = skeys[cbn + bx];
            const bool valid = (keyx != ~0ull);
            const float4 bv = valid ? bbase[(uint32_t)keyx] : F4INV;
            const float  av = box_area(bv);
            int dead = valid ? 0 : 1;
            #pragma unroll 4
            for (int i = q; i < W; i += 4) {             // no early exit -> loads pipeline
                dead |= iou_gt(swbox[i], swarea[i], bv, av) ? 1 : 0;
            }
            dead |= __shfl_xor(dead, 1, 64);
            dead |= __shfl_xor(dead, 2, 64);
            if (q == 0) sdead[bx] = (unsigned char)dead;
        }
        __syncthreads();
        cur ^= 1;
    }

    // epilogue: winners already hold their sorted keys; add class base to index
    const uint32_t  base = (uint32_t)(c - 1) * A_N;
    uint64_t* const out  = ws_keys + ((size_t)b * CF + (c - 1)) * TOPK;
    for (int k2 = t; k2 < TOPK; k2 += CTHREADS) {
        if (k2 < W) {
            const uint64_t kk2 = swkey[k2];
            out[k2] = (kk2 & 0xFFFFFFFF00000000ull) | (uint64_t)(base + (uint32_t)kk2);
        } else {
            out[k2] = ~0ull;
        }
    }
}

// ---- mono fallback (R4 kernel, verified) for tiny ws ----
__global__ __launch_bounds__(THREADS)
void nms_mono(const float* __restrict__ locs,
              const float* __restrict__ scores,
              const float* __restrict__ anchors,
              uint64_t* __restrict__ ws_keys)
{
    __shared__ uint64_t      skeys[SORT_N];
    __shared__ float4        sbox[A_N];
    __shared__ float4        schunk[CH];
    __shared__ uint64_t      srow[CH][2];
    __shared__ float4        swbox[TOPK];
    __shared__ uint64_t      swkey[TOPK];
    __shared__ unsigned char sdead[CH];
    __shared__ int           sW;

    const int blk = blockIdx.x;
    const int b   = blk / CF;
    const int c   = blk % CF + 1;
    const int t   = threadIdx.x;
    const int l   = t & 63;
    const int w   = t >> 6;

    #pragma unroll
    for (int i = 0; i < A_N / THREADS; ++i) {
        const int a = t + i * THREADS;
        const float4 v = decode_box(((const float4*)locs)[(size_t)b * A_N + a],
                                    ((const float4*)anchors)[a]);
        const float* sp = scores + ((size_t)b * A_N + a) * NC;
        float m = sp[0];
        #pragma unroll
        for (int kq = 1; kq < NC; ++kq) m = fmaxf(m, sp[kq]);
        float sum = 0.0f;
        #pragma unroll
        for (int kq = 0; kq < NC; ++kq) sum += expf(sp[kq] - m);
        sbox[a] = v;
        const float sc = expf(sp[c] - m) / sum;
        skeys[a] = (sc > 0.01f) ? pack_key(sc, (uint32_t)a) : ~0ull;
    }
    for (int i = A_N + t; i < SORT_N; i += THREADS) skeys[i] = ~0ull;
    if (t == 0) sW = 0;
    __syncthreads();

    uint64_t k[8];
    #pragma unroll
    for (int r = 0; r < 8; ++r) k[r] = skeys[(w << 9) + (r << 6) + l];
    for (int kk = 2; kk <= SORT_N; kk <<= 1) {
        for (int j = kk >> 1; j; j >>= 1) {
            if (j >= 512) {
                __syncthreads();
                #pragma unroll
                for (int r = 0; r < 8; ++r) skeys[(w << 9) + (r << 6) + l] = k[r];
                __syncthreads();
                #pragma unroll
                for (int r = 0; r < 8; ++r) {
                    const int e = (w << 9) + (r << 6) + l;
                    const uint64_t o = skeys[e ^ j];
                    const bool keep_min = (((e & j) == 0) == ((e & kk) == 0));
                    const uint64_t mn = k[r] < o ? k[r] : o;
                    const uint64_t mx = k[r] < o ? o : k[r];
                    k[r] = keep_min ? mn : mx;
                }
            } else if (j >= 64) {
                const int rb = j >> 6;
                #pragma unroll
                for (int r = 0; r < 8; ++r) {
                    if ((r & rb) == 0) {
                        const int p = r | rb;
                        const int e = (w << 9) + (r << 6) + l;
                        const bool up = ((e & kk) == 0);
                        const uint64_t x = k[r], y = k[p];
                        const uint64_t mn = x < y ? x : y;
                        const uint64_t mx = x < y ? y : x;
                        k[r] = up ? mn : mx;
                        k[p] = up ? mx : mn;
                    }
                }
            } else {
                #pragma unroll
                for (int r = 0; r < 8; ++r) {
                    const uint64_t o = (uint64_t)__shfl_xor((unsigned long long)k[r], j, 64);
                    const int e = (w << 9) + (r << 6) + l;
                    const bool keep_min = (((e & j) == 0) == ((e & kk) == 0));
                    const uint64_t mn = k[r] < o ? k[r] : o;
                    const uint64_t mx = k[r] < o ? o : k[r];
                    k[r] = keep_min ? mn : mx;
                }
            }
        }
    }
    __syncthreads();
    #pragma unroll
    for (int r = 0; r < 8; ++r) skeys[(w << 9) + (r << 6) + l] = k[r];
    __syncthreads();

    int W = 0;
    for (int cb = 0; cb < SORT_N; cb += CH) {
        if (skeys[cb] == ~0ull) break;
        if (t < CH) {
            const uint64_t kc = skeys[cb + t];
            const bool v = (kc != ~0ull);
            schunk[t] = v ? sbox[(uint32_t)kc] : F4INV;
            sdead[t]  = v ? 0 : 1;
        }
        __syncthreads();
        const float4 cb0 = schunk[l];
        const float4 cb1 = schunk[64 + l];
        const float  ca0 = box_area(cb0);
        const float  ca1 = box_area(cb1);
        for (int r = w * 32; r < w * 32 + 32; ++r) {
            const float4 rbx = schunk[r];
            const float  ra  = box_area(rbx);
            const uint64_t m0 = __ballot(iou_gt(rbx, ra, cb0, ca0));
            const uint64_t m1 = __ballot(iou_gt(rbx, ra, cb1, ca1));
            if (l == 0) { srow[r][0] = m0; srow[r][1] = m1; }
        }
        {
            const int jj = t >> 1, h = t & 1;
            const float4 bj = schunk[jj];
            const float  aj = box_area(bj);
            int sup = 0;
            for (int w2 = h; w2 < W; w2 += 2) {
                const float4 bw = swbox[w2];
                if (iou_gt(bw, box_area(bw), bj, aj)) { sup = 1; break; }
            }
            sup |= __shfl_xor(sup, 1, 64);
            if (h == 0 && sup) sdead[jj] = 1;
        }
        __syncthreads();
        if (t < 64) {
            bool al0 = !sdead[t];
            bool al1 = !sdead[64 + t];
            int Wl = W;
            while (true) {
                const unsigned long long bal0 = __ballot(al0);
                const unsigned long long bal1 = __ballot(al1);
                if (!(bal0 | bal1)) break;
                const int f = bal0 ? (__ffsll(bal0) - 1) : (64 + __ffsll(bal1) - 1);
                if (t == 0) { swkey[Wl] = skeys[cb + f]; swbox[Wl] = schunk[f]; }
                const uint64_t r0 = srow[f][0];
                const uint64_t r1 = srow[f][1];
                al0 = al0 && !((r0 >> t) & 1);
                al1 = al1 && !((r1 >> t) & 1);
                if (++Wl >= TOPK) break;
            }
            if (t == 0) sW = Wl;
        }
        __syncthreads();
        W = sW;
        if (W >= TOPK) break;
    }

    const uint32_t  base = (uint32_t)(c - 1) * A_N;
    uint64_t* const out  = ws_keys + ((size_t)b * CF + (c - 1)) * TOPK;
    for (int kx = t; kx < TOPK; kx += THREADS) {
        if (kx < W) {
            const uint64_t kk2 = swkey[kx];
            out[kx] = (kk2 & 0xFFFFFFFF00000000ull) | (uint64_t)(base + (uint32_t)kk2);
        } else {
            out[kx] = ~0ull;
        }
    }
}

// ---- merge: per batch top-200 of 20 sorted lists (R2..R10-verified) ----
__global__ __launch_bounds__(THREADS)
void merge_kernel(const float* __restrict__ locs,
                  const float* __restrict__ anchors,
                  const uint64_t* __restrict__ ws_keys,
                  float* __restrict__ out)
{
    __shared__ uint64_t Abuf[20][256];
    __shared__ uint64_t Bbuf[10][256];

    const int b = blockIdx.x;
    const int t = threadIdx.x;
    const uint64_t* const in = ws_keys + (size_t)b * CF * TOPK;

    for (int e = t; e < CF * 256; e += THREADS) {
        const int c = e >> 8, i = e & 255;
        Abuf[c][i] = (i < TOPK) ? in[c * TOPK + i] : ~0ull;
    }

    uint64_t (*src)[256] = Abuf;
    uint64_t (*dst)[256] = Bbuf;
    int n = CF;
    while (n > 1) {
        const int  nm    = n >> 1;
        const bool carry = (n & 1) != 0;
        __syncthreads();
        for (int e = t; e < nm * 256; e += THREADS) {
            const int mm = e >> 8, i = e & 255;
            const uint64_t x = src[2 * mm][i];
            const uint64_t y = src[2 * mm + 1][255 - i];
            dst[mm][i] = x < y ? x : y;              // lower-half extraction (bitonic)
        }
        if (carry)
            for (int i = t; i < 256; i += THREADS) dst[nm][i] = src[n - 1][i];
        for (int j = 128; j; j >>= 1) {
            __syncthreads();
            for (int pp = t; pp < nm * 128; pp += THREADS) {
                const int mm = pp >> 7, qq = pp & 127;
                const int i  = ((qq & ~(j - 1)) << 1) | (qq & (j - 1));
                const uint64_t x = dst[mm][i], y = dst[mm][i + j];
                if (y < x) { dst[mm][i] = y; dst[mm][i + j] = x; }
            }
        }
        uint64_t (*tmp)[256] = src; src = dst; dst = tmp;
        n = nm + (carry ? 1 : 0);
    }
    __syncthreads();

    if (t < TOPK) {
        const uint64_t k = src[0][t];
        float* const boxes_out  = out;                           // [B][TOPK][4]
        float* const labels_out = out + (size_t)B_N * TOPK * 4;  // [B][TOPK]
        float* const scores_out = out + (size_t)B_N * TOPK * 5;  // [B][TOPK]
        const size_t s = (size_t)b * TOPK + t;
        if (k == ~0ull) {
            boxes_out[s * 4 + 0] = 0.0f;
            boxes_out[s * 4 + 1] = 0.0f;
            boxes_out[s * 4 + 2] = 0.0f;
            boxes_out[s * 4 + 3] = 0.0f;
            labels_out[s] = 0.0f;
            scores_out[s] = 0.0f;
        } else {
            const uint32_t flat = (uint32_t)k;
            const int cls = flat / A_N;          // 0..19
            const int a   = flat - cls * A_N;
            const float sc = __uint_as_float(~(uint32_t)(k >> 32));
            const float4 v = decode_box(((const float4*)locs)[(size_t)b * A_N + a],
                                        ((const float4*)anchors)[a]);
            boxes_out[s * 4 + 0] = v.x;
            boxes_out[s * 4 + 1] = v.y;
            boxes_out[s * 4 + 2] = v.z;
            boxes_out[s * 4 + 3] = v.w;
            labels_out[s] = (float)(cls + 1);
            scores_out[s] = sc;
        }
    }
}

extern "C" void kernel_launch(void* const* d_in, const int* in_sizes, int n_in,
                              void* d_out, int out_size, void* d_ws, size_t ws_size,
                              hipStream_t stream) {
    const float* locs    = (const float*)d_in[0];
    const float* scores  = (const float*)d_in[1];
    const float* anchors = (const float*)d_in[2];
    uint64_t* ws_keys  = (uint64_t*)d_ws;
    float4*   boxes_ws = (float4*)((char*)d_ws + BOX_OFF);
    float2*   ms_ws    = (float2*)((char*)d_ws + MS_OFF);
    float*    outp     = (float*)d_out;

    if (ws_size >= (size_t)WS_B_BYTES) {
        hipLaunchKernelGGL(prep_kernel, dim3((B_N * A_N + THREADS - 1) / THREADS),
                           dim3(THREADS), 0, stream, locs, scores, anchors, boxes_ws, ms_ws);
        hipLaunchKernelGGL(fused_nms_kernel, dim3(B_N * CF), dim3(CTHREADS), 0, stream,
                           scores, ms_ws, boxes_ws, ws_keys);
    } else {
        hipLaunchKernelGGL(nms_mono, dim3(B_N * CF), dim3(THREADS), 0, stream,
                           locs, scores, anchors, ws_keys);
    }
    hipLaunchKernelGGL(merge_kernel, dim3(B_N), dim3(THREADS), 0, stream,
                       locs, anchors, ws_keys, outp);
}

// Round 12
// 183.049 us; speedup vs baseline: 1.2192x; 1.2192x over previous
//
#include <hip/hip_runtime.h>
#include <stdint.h>

// DetectionBaseline: SSD post-process. R12 = R10 (best, 171 us) + ONE change:
//  sort uses 4 waves x 8 regs (R4-verified e=(w<<9)|(r<<6)|l): j in {64,128,256}
//  are in-register exchanges -> 3 LDS round-trips (6 barriers) instead of 6 (12).
//  Chunk loop / P1 / P2 / P3 byte-identical to R10 (verified absmax 0.0).
//   prep      : per (b,a) box decode + softmax (m,sum)   [batch-shared]
//   fused_nms : per (b,c): key build -> sort -> chunked greedy NMS
//   merge     : per b truncated pairwise bitonic merges -> top-200 output

#define A_N     1280
#define CF      20
#define NC      21
#define B_N     16
#define TOPK    200
#define THREADS 256
#define CTHREADS 512
#define SORT_N  2048
#define CH      128

// ws layout (bytes)
#define KEYS_BYTES   (B_N * CF * TOPK * 8)                 // 512000 kept-key lists
#define BOX_OFF      KEYS_BYTES                             // float4 [16*1280] = 327680
#define MS_OFF       (BOX_OFF + B_N * A_N * 16)             // float2 [16*1280] = 163840
#define WS_B_BYTES   (MS_OFF + B_N * A_N * 8)               // 1003520 (fused tier)

#define F4INV make_float4(-8.f, -8.f, -8.f, -8.f)

static __device__ __forceinline__ uint64_t pack_key(float sc, uint32_t idx) {
    // softmax scores positive -> float bits monotone. ~bits => ascending key = descending
    // score; low 32 bits = index => ties break toward smaller index (stable argsort / top_k).
    return ((uint64_t)(uint32_t)(~__float_as_uint(sc)) << 32) | (uint64_t)idx;
}

static __device__ __forceinline__ float box_area(const float4 v) {
    return (v.z - v.x) * (v.w - v.y);
}

static __device__ __forceinline__ bool iou_gt(const float4 a, const float aarea,
                                              const float4 b, const float barea) {
    // ref-exact: inter/(area_a + area_b - inter) > 0.45; exactly symmetric in IEEE
    const float lx = fmaxf(a.x, b.x);
    const float ly = fmaxf(a.y, b.y);
    const float rx = fminf(a.z, b.z);
    const float ry = fminf(a.w, b.w);
    const float wx = fmaxf(rx - lx, 0.0f);
    const float wy = fmaxf(ry - ly, 0.0f);
    const float inter = wx * wy;
    const float uni   = aarea + barea - inter;
    return inter / uni > 0.45f;
}

static __device__ __forceinline__ float4 decode_box(const float4 lc, const float4 an) {
    const float cx = lc.x * an.z / 10.0f + an.x;
    const float cy = lc.y * an.w / 10.0f + an.y;
    const float w  = expf(lc.z / 5.0f) * an.z;
    const float h  = expf(lc.w / 5.0f) * an.w;
    float4 v;
    v.x = cx - w / 2.0f; v.y = cy - h / 2.0f;
    v.z = cx + w / 2.0f; v.w = cy + h / 2.0f;
    return v;
}

static __device__ __forceinline__ float4 shfl_box(const float4 v, int lane) {
    float4 r;
    r.x = __shfl(v.x, lane, 64);
    r.y = __shfl(v.y, lane, 64);
    r.z = __shfl(v.z, lane, 64);
    r.w = __shfl(v.w, lane, 64);
    return r;
}

static __device__ __forceinline__ uint64_t readlane_u64(uint64_t v, int lane) {
    const uint32_t lo = (uint32_t)__builtin_amdgcn_readlane((int)(uint32_t)v, lane);
    const uint32_t hi = (uint32_t)__builtin_amdgcn_readlane((int)(uint32_t)(v >> 32), lane);
    return ((uint64_t)hi << 32) | lo;
}

// ---- prep: per (b,a) decoded box + softmax (max, sum) ----
__global__ __launch_bounds__(THREADS)
void prep_kernel(const float* __restrict__ locs,
                 const float* __restrict__ scores,
                 const float* __restrict__ anchors,
                 float4* __restrict__ boxes_ws,
                 float2* __restrict__ ms_ws)
{
    const int g = blockIdx.x * THREADS + threadIdx.x;
    if (g >= B_N * A_N) return;
    const int a = g % A_N;
    boxes_ws[g] = decode_box(((const float4*)locs)[g], ((const float4*)anchors)[a]);
    const float* sp = scores + (size_t)g * NC;
    float m = sp[0];
    #pragma unroll
    for (int k = 1; k < NC; ++k) m = fmaxf(m, sp[k]);
    float sum = 0.0f;
    #pragma unroll
    for (int k = 0; k < NC; ++k) sum += expf(sp[k] - m);
    ms_ws[g] = make_float2(m, sum);
}

// ---- fused_nms (512 threads): key build + 4-wave/8-reg sort + chunked NMS ----
__global__ __launch_bounds__(CTHREADS)
void fused_nms_kernel(const float* __restrict__ scores,
                      const float2* __restrict__ ms_ws,
                      const float4* __restrict__ boxes_ws,
                      uint64_t* __restrict__ ws_keys)
{
    __shared__ uint64_t      skeys[SORT_N];   // 16 KB sorted keys
    __shared__ uint64_t      srow[CH][2];     // kill rows, 128 bits each
    __shared__ unsigned char sdead[CH];
    __shared__ float4        swbox[TOPK];     // winner boxes (cross-test)
    __shared__ float         swarea[TOPK];    // winner areas
    __shared__ uint64_t      swkey[TOPK];     // winner sorted keys (rank order)
    __shared__ int           sW;

    const int blk = blockIdx.x;
    const int b   = blk / CF;
    const int c   = blk % CF + 1;             // class channel 1..20
    const int t   = threadIdx.x;              // 0..511
    const int l   = t & 63;
    const int w   = t >> 6;                   // 0..7

    // ---- key build (ref-exact softmax from prep's m,sum) ----
    #pragma unroll
    for (int i = 0; i < SORT_N / CTHREADS; ++i) {
        const int a = t + i * CTHREADS;
        if (a < A_N) {
            const float2 ms = ms_ws[b * A_N + a];
            const float  sl = scores[((size_t)b * A_N + a) * NC + c];
            const float  sc = expf(sl - ms.x) / ms.y;
            skeys[a] = (sc > 0.01f) ? pack_key(sc, (uint32_t)a) : ~0ull;
        } else {
            skeys[a] = ~0ull;
        }
    }
    if (t == 0) sW = 0;
    __syncthreads();

    // ---- register/wave bitonic sort: waves 0-3, 8 keys/thread, e=(w<<9)|(r<<6)|l
    //      (R4-R7-verified layout; j in {64,128,256} in-register -> 3 LDS rounds) ----
    const bool sorter = (w < 4);
    uint64_t k[8];
    if (sorter) {
        #pragma unroll
        for (int r = 0; r < 8; ++r) k[r] = skeys[(w << 9) + (r << 6) + l];
    }
    for (int kk = 2; kk <= SORT_N; kk <<= 1) {
        for (int j = kk >> 1; j; j >>= 1) {       // uniform loop -> barriers uniform
            if (j >= 512) {
                __syncthreads();
                if (sorter) {
                    #pragma unroll
                    for (int r = 0; r < 8; ++r) skeys[(w << 9) + (r << 6) + l] = k[r];
                }
                __syncthreads();
                if (sorter) {
                    #pragma unroll
                    for (int r = 0; r < 8; ++r) {
                        const int e = (w << 9) + (r << 6) + l;
                        const uint64_t o = skeys[e ^ j];
                        const bool keep_min = (((e & j) == 0) == ((e & kk) == 0));
                        const uint64_t mn = k[r] < o ? k[r] : o;
                        const uint64_t mx = k[r] < o ? o : k[r];
                        k[r] = keep_min ? mn : mx;
                    }
                }
            } else if (j >= 64) {
                if (sorter) {
                    const int rb = j >> 6;            // 1, 2, or 4
                    #pragma unroll
                    for (int r = 0; r < 8; ++r) {
                        if ((r & rb) == 0) {
                            const int p = r | rb;
                            const int e = (w << 9) + (r << 6) + l;
                            const bool up = ((e & kk) == 0);
                            const uint64_t x = k[r], y = k[p];
                            const uint64_t mn = x < y ? x : y;
                            const uint64_t mx = x < y ? y : x;
                            k[r] = up ? mn : mx;
                            k[p] = up ? mx : mn;
                        }
                    }
                }
            } else {
                if (sorter) {
                    #pragma unroll
                    for (int r = 0; r < 8; ++r) {
                        const uint64_t o = (uint64_t)__shfl_xor((unsigned long long)k[r], j, 64);
                        const int e = (w << 9) + (r << 6) + l;
                        const bool keep_min = (((e & j) == 0) == ((e & kk) == 0));
                        const uint64_t mn = k[r] < o ? k[r] : o;
                        const uint64_t mx = k[r] < o ? o : k[r];
                        k[r] = keep_min ? mn : mx;
                    }
                }
            }
        }
    }
    __syncthreads();   // last LDS-pass readers done before overwrite
    if (sorter) {
        #pragma unroll
        for (int r = 0; r < 8; ++r) skeys[(w << 9) + (r << 6) + l] = k[r];
    }
    __syncthreads();

    // ---- chunked greedy NMS (R10-verbatim 3-phase body) ----
    const float4* const bbase = boxes_ws + (size_t)b * A_N;
    int W = 0;
    for (int cb = 0; cb < A_N; cb += CH) {
        if (skeys[cb] == ~0ull) break;        // sorted: rest invalid (uniform)

        // column boxes: lane l holds cols l and 64+l (L2-hot loads)
        const uint64_t key0 = skeys[cb + l];
        const uint64_t key1 = skeys[cb + 64 + l];
        const bool v0 = (key0 != ~0ull), v1 = (key1 != ~0ull);
        const float4 box_lo = v0 ? bbase[(uint32_t)key0] : F4INV;
        const float4 box_hi = v1 ? bbase[(uint32_t)key1] : F4INV;
        const float  al = box_area(box_lo);
        const float  ah = box_area(box_hi);

        // P1: cross-test vs prior winners, 4 helpers per box (pipelined, no early exit)
        {
            const int bx = t >> 2, q = t & 3;
            const uint64_t keyx = skeys[cb + bx];
            const bool valid = (keyx != ~0ull);
            const float4 bv = valid ? bbase[(uint32_t)keyx] : F4INV;
            const float  av = box_area(bv);
            int dead = valid ? 0 : 1;
            #pragma unroll 4
            for (int i = q; i < W; i += 4) {
                dead |= iou_gt(swbox[i], swarea[i], bv, av) ? 1 : 0;
            }
            dead |= __shfl_xor(dead, 1, 64);
            dead |= __shfl_xor(dead, 2, 64);
            if (q == 0) sdead[bx] = (unsigned char)dead;
        }
        __syncthreads();

        // P2: sparse alive-row kill-matrix build; wave w owns rows [16w,16w+16)
        {
            const int rbase = w * 16;
            uint32_t rm = (uint32_t)__ballot(l < 16 && !sdead[rbase + l]) & 0xFFFFu;
            while (rm) {                          // uniform per wave (ballot result)
                const int j = __ffs(rm) - 1; rm &= rm - 1;
                const int row = rbase + j;
                const float4 rowsrc = (row < 64) ? box_lo : box_hi;
                const float4 rbx = shfl_box(rowsrc, row & 63);
                const float  ra  = box_area(rbx);
                const uint64_t m0 = __ballot(iou_gt(rbx, ra, box_lo, al));
                const uint64_t m1 = __ballot(iou_gt(rbx, ra, box_hi, ah));
                if (l == 0) { srow[row][0] = m0; srow[row][1] = m1; }
            }
        }
        __syncthreads();

        // P3: wave-0 scalar resolve: ctz + readlane + andn per winner (R8-verified)
        if (w == 0) {
            const uint64_t r0lo = srow[l][0];        // row l
            const uint64_t r0hi = srow[l][1];
            const uint64_t r1lo = srow[64 + l][0];   // row 64+l
            const uint64_t r1hi = srow[64 + l][1];
            uint64_t alive0 = __ballot(sdead[l] == 0);
            uint64_t alive1 = __ballot(sdead[64 + l] == 0);
            int Wl = W;
            while ((alive0 | alive1) && Wl < TOPK) {
                const int f = alive0 ? __builtin_ctzll(alive0)
                                     : 64 + __builtin_ctzll(alive1);
                if (f < 64) {
                    if (l == f)      { swkey[Wl] = key0; swbox[Wl] = box_lo; swarea[Wl] = al; }
                } else {
                    if (l == f - 64) { swkey[Wl] = key1; swbox[Wl] = box_hi; swarea[Wl] = ah; }
                }
                uint64_t klo, khi;
                if (f < 64) { klo = readlane_u64(r0lo, f);      khi = readlane_u64(r0hi, f); }
                else        { klo = readlane_u64(r1lo, f - 64); khi = readlane_u64(r1hi, f - 64); }
                alive0 &= ~klo;                  // winner self-clears (diag IoU = 1)
                alive1 &= ~khi;
                ++Wl;
            }
            if (l == 0) sW = Wl;
        }
        __syncthreads();
        W = sW;
        if (W >= TOPK) break;
    }

    // epilogue: winners already hold their sorted keys; add class base to index
    const uint32_t  base = (uint32_t)(c - 1) * A_N;
    uint64_t* const out  = ws_keys + ((size_t)b * CF + (c - 1)) * TOPK;
    for (int k2 = t; k2 < TOPK; k2 += CTHREADS) {
        if (k2 < W) {
            const uint64_t kk2 = swkey[k2];
            out[k2] = (kk2 & 0xFFFFFFFF00000000ull) | (uint64_t)(base + (uint32_t)kk2);
        } else {
            out[k2] = ~0ull;
        }
    }
}

// ---- mono fallback (R4 kernel, verified) for tiny ws ----
__global__ __launch_bounds__(THREADS)
void nms_mono(const float* __restrict__ locs,
              const float* __restrict__ scores,
              const float* __restrict__ anchors,
              uint64_t* __restrict__ ws_keys)
{
    __shared__ uint64_t      skeys[SORT_N];
    __shared__ float4        sbox[A_N];
    __shared__ float4        schunk[CH];
    __shared__ uint64_t      srow[CH][2];
    __shared__ float4        swbox[TOPK];
    __shared__ uint64_t      swkey[TOPK];
    __shared__ unsigned char sdead[CH];
    __shared__ int           sW;

    const int blk = blockIdx.x;
    const int b   = blk / CF;
    const int c   = blk % CF + 1;
    const int t   = threadIdx.x;
    const int l   = t & 63;
    const int w   = t >> 6;

    #pragma unroll
    for (int i = 0; i < A_N / THREADS; ++i) {
        const int a = t + i * THREADS;
        const float4 v = decode_box(((const float4*)locs)[(size_t)b * A_N + a],
                                    ((const float4*)anchors)[a]);
        const float* sp = scores + ((size_t)b * A_N + a) * NC;
        float m = sp[0];
        #pragma unroll
        for (int kq = 1; kq < NC; ++kq) m = fmaxf(m, sp[kq]);
        float sum = 0.0f;
        #pragma unroll
        for (int kq = 0; kq < NC; ++kq) sum += expf(sp[kq] - m);
        sbox[a] = v;
        const float sc = expf(sp[c] - m) / sum;
        skeys[a] = (sc > 0.01f) ? pack_key(sc, (uint32_t)a) : ~0ull;
    }
    for (int i = A_N + t; i < SORT_N; i += THREADS) skeys[i] = ~0ull;
    if (t == 0) sW = 0;
    __syncthreads();

    uint64_t k[8];
    #pragma unroll
    for (int r = 0; r < 8; ++r) k[r] = skeys[(w << 9) + (r << 6) + l];
    for (int kk = 2; kk <= SORT_N; kk <<= 1) {
        for (int j = kk >> 1; j; j >>= 1) {
            if (j >= 512) {
                __syncthreads();
                #pragma unroll
                for (int r = 0; r < 8; ++r) skeys[(w << 9) + (r << 6) + l] = k[r];
                __syncthreads();
                #pragma unroll
                for (int r = 0; r < 8; ++r) {
                    const int e = (w << 9) + (r << 6) + l;
                    const uint64_t o = skeys[e ^ j];
                    const bool keep_min = (((e & j) == 0) == ((e & kk) == 0));
                    const uint64_t mn = k[r] < o ? k[r] : o;
                    const uint64_t mx = k[r] < o ? o : k[r];
                    k[r] = keep_min ? mn : mx;
                }
            } else if (j >= 64) {
                const int rb = j >> 6;
                #pragma unroll
                for (int r = 0; r < 8; ++r) {
                    if ((r & rb) == 0) {
                        const int p = r | rb;
                        const int e = (w << 9) + (r << 6) + l;
                        const bool up = ((e & kk) == 0);
                        const uint64_t x = k[r], y = k[p];
                        const uint64_t mn = x < y ? x : y;
                        const uint64_t mx = x < y ? y : x;
                        k[r] = up ? mn : mx;
                        k[p] = up ? mx : mn;
                    }
                }
            } else {
                #pragma unroll
                for (int r = 0; r < 8; ++r) {
                    const uint64_t o = (uint64_t)__shfl_xor((unsigned long long)k[r], j, 64);
                    const int e = (w << 9) + (r << 6) + l;
                    const bool keep_min = (((e & j) == 0) == ((e & kk) == 0));
                    const uint64_t mn = k[r] < o ? k[r] : o;
                    const uint64_t mx = k[r] < o ? o : k[r];
                    k[r] = keep_min ? mn : mx;
                }
            }
        }
    }
    __syncthreads();
    #pragma unroll
    for (int r = 0; r < 8; ++r) skeys[(w << 9) + (r << 6) + l] = k[r];
    __syncthreads();

    int W = 0;
    for (int cb = 0; cb < SORT_N; cb += CH) {
        if (skeys[cb] == ~0ull) break;
        if (t < CH) {
            const uint64_t kc = skeys[cb + t];
            const bool v = (kc != ~0ull);
            schunk[t] = v ? sbox[(uint32_t)kc] : F4INV;
            sdead[t]  = v ? 0 : 1;
        }
        __syncthreads();
        const float4 cb0 = schunk[l];
        const float4 cb1 = schunk[64 + l];
        const float  ca0 = box_area(cb0);
        const float  ca1 = box_area(cb1);
        for (int r = w * 32; r < w * 32 + 32; ++r) {
            const float4 rbx = schunk[r];
            const float  ra  = box_area(rbx);
            const uint64_t m0 = __ballot(iou_gt(rbx, ra, cb0, ca0));
            const uint64_t m1 = __ballot(iou_gt(rbx, ra, cb1, ca1));
            if (l == 0) { srow[r][0] = m0; srow[r][1] = m1; }
        }
        {
            const int jj = t >> 1, h = t & 1;
            const float4 bj = schunk[jj];
            const float  aj = box_area(bj);
            int sup = 0;
            for (int w2 = h; w2 < W; w2 += 2) {
                const float4 bw = swbox[w2];
                if (iou_gt(bw, box_area(bw), bj, aj)) { sup = 1; break; }
            }
            sup |= __shfl_xor(sup, 1, 64);
            if (h == 0 && sup) sdead[jj] = 1;
        }
        __syncthreads();
        if (t < 64) {
            bool al0 = !sdead[t];
            bool al1 = !sdead[64 + t];
            int Wl = W;
            while (true) {
                const unsigned long long bal0 = __ballot(al0);
                const unsigned long long bal1 = __ballot(al1);
                if (!(bal0 | bal1)) break;
                const int f = bal0 ? (__ffsll(bal0) - 1) : (64 + __ffsll(bal1) - 1);
                if (t == 0) { swkey[Wl] = skeys[cb + f]; swbox[Wl] = schunk[f]; }
                const uint64_t r0 = srow[f][0];
                const uint64_t r1 = srow[f][1];
                al0 = al0 && !((r0 >> t) & 1);
                al1 = al1 && !((r1 >> t) & 1);
                if (++Wl >= TOPK) break;
            }
            if (t == 0) sW = Wl;
        }
        __syncthreads();
        W = sW;
        if (W >= TOPK) break;
    }

    const uint32_t  base = (uint32_t)(c - 1) * A_N;
    uint64_t* const out  = ws_keys + ((size_t)b * CF + (c - 1)) * TOPK;
    for (int kx = t; kx < TOPK; kx += THREADS) {
        if (kx < W) {
            const uint64_t kk2 = swkey[kx];
            out[kx] = (kk2 & 0xFFFFFFFF00000000ull) | (uint64_t)(base + (uint32_t)kk2);
        } else {
            out[kx] = ~0ull;
        }
    }
}

// ---- merge: per batch top-200 of 20 sorted lists (R2..R11-verified) ----
__global__ __launch_bounds__(THREADS)
void merge_kernel(const float* __restrict__ locs,
                  const float* __restrict__ anchors,
                  const uint64_t* __restrict__ ws_keys,
                  float* __restrict__ out)
{
    __shared__ uint64_t Abuf[20][256];
    __shared__ uint64_t Bbuf[10][256];

    const int b = blockIdx.x;
    const int t = threadIdx.x;
    const uint64_t* const in = ws_keys + (size_t)b * CF * TOPK;

    for (int e = t; e < CF * 256; e += THREADS) {
        const int c = e >> 8, i = e & 255;
        Abuf[c][i] = (i < TOPK) ? in[c * TOPK + i] : ~0ull;
    }

    uint64_t (*src)[256] = Abuf;
    uint64_t (*dst)[256] = Bbuf;
    int n = CF;
    while (n > 1) {
        const int  nm    = n >> 1;
        const bool carry = (n & 1) != 0;
        __syncthreads();
        for (int e = t; e < nm * 256; e += THREADS) {
            const int mm = e >> 8, i = e & 255;
            const uint64_t x = src[2 * mm][i];
            const uint64_t y = src[2 * mm + 1][255 - i];
            dst[mm][i] = x < y ? x : y;              // lower-half extraction (bitonic)
        }
        if (carry)
            for (int i = t; i < 256; i += THREADS) dst[nm][i] = src[n - 1][i];
        for (int j = 128; j; j >>= 1) {
            __syncthreads();
            for (int pp = t; pp < nm * 128; pp += THREADS) {
                const int mm = pp >> 7, qq = pp & 127;
                const int i  = ((qq & ~(j - 1)) << 1) | (qq & (j - 1));
                const uint64_t x = dst[mm][i], y = dst[mm][i + j];
                if (y < x) { dst[mm][i] = y; dst[mm][i + j] = x; }
            }
        }
        uint64_t (*tmp)[256] = src; src = dst; dst = tmp;
        n = nm + (carry ? 1 : 0);
    }
    __syncthreads();

    if (t < TOPK) {
        const uint64_t k = src[0][t];
        float* const boxes_out  = out;                           // [B][TOPK][4]
        float* const labels_out = out + (size_t)B_N * TOPK * 4;  // [B][TOPK]
        float* const scores_out = out + (size_t)B_N * TOPK * 5;  // [B][TOPK]
        const size_t s = (size_t)b * TOPK + t;
        if (k == ~0ull) {
            boxes_out[s * 4 + 0] = 0.0f;
            boxes_out[s * 4 + 1] = 0.0f;
            boxes_out[s * 4 + 2] = 0.0f;
            boxes_out[s * 4 + 3] = 0.0f;
            labels_out[s] = 0.0f;
            scores_out[s] = 0.0f;
        } else {
            const uint32_t flat = (uint32_t)k;
            const int cls = flat / A_N;          // 0..19
            const int a   = flat - cls * A_N;
            const float sc = __uint_as_float(~(uint32_t)(k >> 32));
            const float4 v = decode_box(((const float4*)locs)[(size_t)b * A_N + a],
                                        ((const float4*)anchors)[a]);
            boxes_out[s * 4 + 0] = v.x;
            boxes_out[s * 4 + 1] = v.y;
            boxes_out[s * 4 + 2] = v.z;
            boxes_out[s * 4 + 3] = v.w;
            labels_out[s] = (float)(cls + 1);
            scores_out[s] = sc;
        }
    }
}

extern "C" void kernel_launch(void* const* d_in, const int* in_sizes, int n_in,
                              void* d_out, int out_size, void* d_ws, size_t ws_size,
                              hipStream_t stream) {
    const float* locs    = (const float*)d_in[0];
    const float* scores  = (const float*)d_in[1];
    const float* anchors = (const float*)d_in[2];
    uint64_t* ws_keys  = (uint64_t*)d_ws;
    float4*   boxes_ws = (float4*)((char*)d_ws + BOX_OFF);
    float2*   ms_ws    = (float2*)((char*)d_ws + MS_OFF);
    float*    outp     = (float*)d_out;

    if (ws_size >= (size_t)WS_B_BYTES) {
        hipLaunchKernelGGL(prep_kernel, dim3((B_N * A_N + THREADS - 1) / THREADS),
                           dim3(THREADS), 0, stream, locs, scores, anchors, boxes_ws, ms_ws);
        hipLaunchKernelGGL(fused_nms_kernel, dim3(B_N * CF), dim3(CTHREADS), 0, stream,
                           scores, ms_ws, boxes_ws, ws_keys);
    } else {
        hipLaunchKernelGGL(nms_mono, dim3(B_N * CF), dim3(THREADS), 0, stream,
                           locs, scores, anchors, ws_keys);
    }
    hipLaunchKernelGGL(merge_kernel, dim3(B_N), dim3(THREADS), 0, stream,
                       locs, anchors, ws_keys, outp);
}

// Round 13
// 171.112 us; speedup vs baseline: 1.3042x; 1.0698x over previous
//
#include <hip/hip_runtime.h>
#include <stdint.h>

// DetectionBaseline: SSD post-process. R13 = R10 restored verbatim (session best:
// 171 us total, fused 153 us, absmax 0.0). R11 (pipelined P2) and R12 (4-wave sort)
// both regressed — R10's dense 3-phase structure is the measured local optimum.
//   prep      : per (b,a) box decode + softmax (m,sum)   [batch-shared]
//   fused_nms : per (b,c): key build -> register bitonic sort -> chunked greedy NMS
//   merge     : per b truncated pairwise bitonic merges -> top-200 output

#define A_N     1280
#define CF      20
#define NC      21
#define B_N     16
#define TOPK    200
#define THREADS 256
#define CTHREADS 512
#define SORT_N  2048
#define CH      128

// ws layout (bytes)
#define KEYS_BYTES   (B_N * CF * TOPK * 8)                 // 512000 kept-key lists
#define BOX_OFF      KEYS_BYTES                             // float4 [16*1280] = 327680
#define MS_OFF       (BOX_OFF + B_N * A_N * 16)             // float2 [16*1280] = 163840
#define WS_B_BYTES   (MS_OFF + B_N * A_N * 8)               // 1003520 (fused tier)

static __device__ __forceinline__ uint64_t pack_key(float sc, uint32_t idx) {
    // softmax scores positive -> float bits monotone. ~bits => ascending key = descending
    // score; low 32 bits = index => ties break toward smaller index (stable argsort / top_k).
    return ((uint64_t)(uint32_t)(~__float_as_uint(sc)) << 32) | (uint64_t)idx;
}

static __device__ __forceinline__ float box_area(const float4 v) {
    return (v.z - v.x) * (v.w - v.y);
}

static __device__ __forceinline__ bool iou_gt(const float4 a, const float aarea,
                                              const float4 b, const float barea) {
    // ref-exact: inter/(area_a + area_b - inter) > 0.45; exactly symmetric in IEEE
    const float lx = fmaxf(a.x, b.x);
    const float ly = fmaxf(a.y, b.y);
    const float rx = fminf(a.z, b.z);
    const float ry = fminf(a.w, b.w);
    const float wx = fmaxf(rx - lx, 0.0f);
    const float wy = fmaxf(ry - ly, 0.0f);
    const float inter = wx * wy;
    const float uni   = aarea + barea - inter;
    return inter / uni > 0.45f;
}

static __device__ __forceinline__ float4 decode_box(const float4 lc, const float4 an) {
    const float cx = lc.x * an.z / 10.0f + an.x;
    const float cy = lc.y * an.w / 10.0f + an.y;
    const float w  = expf(lc.z / 5.0f) * an.z;
    const float h  = expf(lc.w / 5.0f) * an.w;
    float4 v;
    v.x = cx - w / 2.0f; v.y = cy - h / 2.0f;
    v.z = cx + w / 2.0f; v.w = cy + h / 2.0f;
    return v;
}

static __device__ __forceinline__ float4 shfl_box(const float4 v, int lane) {
    float4 r;
    r.x = __shfl(v.x, lane, 64);
    r.y = __shfl(v.y, lane, 64);
    r.z = __shfl(v.z, lane, 64);
    r.w = __shfl(v.w, lane, 64);
    return r;
}

static __device__ __forceinline__ uint64_t readlane_u64(uint64_t v, int lane) {
    const uint32_t lo = (uint32_t)__builtin_amdgcn_readlane((int)(uint32_t)v, lane);
    const uint32_t hi = (uint32_t)__builtin_amdgcn_readlane((int)(uint32_t)(v >> 32), lane);
    return ((uint64_t)hi << 32) | lo;
}

// ---- prep: per (b,a) decoded box + softmax (max, sum) ----
__global__ __launch_bounds__(THREADS)
void prep_kernel(const float* __restrict__ locs,
                 const float* __restrict__ scores,
                 const float* __restrict__ anchors,
                 float4* __restrict__ boxes_ws,
                 float2* __restrict__ ms_ws)
{
    const int g = blockIdx.x * THREADS + threadIdx.x;
    if (g >= B_N * A_N) return;
    const int a = g % A_N;
    boxes_ws[g] = decode_box(((const float4*)locs)[g], ((const float4*)anchors)[a]);
    const float* sp = scores + (size_t)g * NC;
    float m = sp[0];
    #pragma unroll
    for (int k = 1; k < NC; ++k) m = fmaxf(m, sp[k]);
    float sum = 0.0f;
    #pragma unroll
    for (int k = 0; k < NC; ++k) sum += expf(sp[k] - m);
    ms_ws[g] = make_float2(m, sum);
}

// ---- fused_nms (512 threads): key build + register bitonic sort + chunked NMS ----
__global__ __launch_bounds__(CTHREADS)
void fused_nms_kernel(const float* __restrict__ scores,
                      const float2* __restrict__ ms_ws,
                      const float4* __restrict__ boxes_ws,
                      uint64_t* __restrict__ ws_keys)
{
    __shared__ uint64_t      skeys[SORT_N];   // 16 KB sorted keys
    __shared__ uint64_t      srow[CH][2];     // kill rows, 128 bits each
    __shared__ unsigned char sdead[CH];
    __shared__ float4        swbox[TOPK];     // winner boxes (cross-test)
    __shared__ float         swarea[TOPK];    // winner areas
    __shared__ uint64_t      swkey[TOPK];     // winner sorted keys (rank order)
    __shared__ int           sW;

    const int blk = blockIdx.x;
    const int b   = blk / CF;
    const int c   = blk % CF + 1;             // class channel 1..20
    const int t   = threadIdx.x;              // 0..511
    const int l   = t & 63;
    const int w   = t >> 6;                   // 0..7

    // ---- key build (ref-exact softmax from prep's m,sum) ----
    #pragma unroll
    for (int i = 0; i < SORT_N / CTHREADS; ++i) {
        const int a = t + i * CTHREADS;
        if (a < A_N) {
            const float2 ms = ms_ws[b * A_N + a];
            const float  sl = scores[((size_t)b * A_N + a) * NC + c];
            const float  sc = expf(sl - ms.x) / ms.y;
            skeys[a] = (sc > 0.01f) ? pack_key(sc, (uint32_t)a) : ~0ull;
        } else {
            skeys[a] = ~0ull;
        }
    }
    if (t == 0) sW = 0;
    __syncthreads();

    // ---- register/wave bitonic sort: 4 keys/thread, e = (w<<8)|(r<<6)|l ----
    uint64_t k[4];
    #pragma unroll
    for (int r = 0; r < 4; ++r) k[r] = skeys[(w << 8) + (r << 6) + l];

    for (int kk = 2; kk <= SORT_N; kk <<= 1) {
        for (int j = kk >> 1; j; j >>= 1) {
            if (j >= 256) {
                // cross-wave: LDS round trip
                __syncthreads();
                #pragma unroll
                for (int r = 0; r < 4; ++r) skeys[(w << 8) + (r << 6) + l] = k[r];
                __syncthreads();
                #pragma unroll
                for (int r = 0; r < 4; ++r) {
                    const int e = (w << 8) + (r << 6) + l;
                    const uint64_t o = skeys[e ^ j];
                    const bool keep_min = (((e & j) == 0) == ((e & kk) == 0));
                    const uint64_t mn = k[r] < o ? k[r] : o;
                    const uint64_t mx = k[r] < o ? o : k[r];
                    k[r] = keep_min ? mn : mx;
                }
            } else if (j >= 64) {
                // in-thread register exchange
                const int rb = j >> 6;                 // 1 or 2
                #pragma unroll
                for (int r = 0; r < 4; ++r) {
                    if ((r & rb) == 0) {
                        const int p = r | rb;
                        const int e = (w << 8) + (r << 6) + l;
                        const bool up = ((e & kk) == 0);
                        const uint64_t x = k[r], y = k[p];
                        const uint64_t mn = x < y ? x : y;
                        const uint64_t mx = x < y ? y : x;
                        k[r] = up ? mn : mx;
                        k[p] = up ? mx : mn;
                    }
                }
            } else {
                // in-wave shuffle exchange
                #pragma unroll
                for (int r = 0; r < 4; ++r) {
                    const uint64_t o = (uint64_t)__shfl_xor((unsigned long long)k[r], j, 64);
                    const int e = (w << 8) + (r << 6) + l;
                    const bool keep_min = (((e & j) == 0) == ((e & kk) == 0));
                    const uint64_t mn = k[r] < o ? k[r] : o;
                    const uint64_t mx = k[r] < o ? o : k[r];
                    k[r] = keep_min ? mn : mx;
                }
            }
        }
    }
    __syncthreads();   // last LDS-pass readers done before overwrite
    #pragma unroll
    for (int r = 0; r < 4; ++r) skeys[(w << 8) + (r << 6) + l] = k[r];
    __syncthreads();

    // ---- chunked greedy NMS (R8-verified body, keys straight from LDS) ----
    const float4* const bbase = boxes_ws + (size_t)b * A_N;
    int W = 0;
    for (int cb = 0; cb < A_N; cb += CH) {
        if (skeys[cb] == ~0ull) break;        // sorted: rest invalid (uniform)

        // column boxes: lane l holds cols l and 64+l (L2-hot loads)
        const uint64_t key0 = skeys[cb + l];
        const uint64_t key1 = skeys[cb + 64 + l];
        const bool v0 = (key0 != ~0ull), v1 = (key1 != ~0ull);
        const float4 box_lo = v0 ? bbase[(uint32_t)key0] : make_float4(-8.f, -8.f, -8.f, -8.f);
        const float4 box_hi = v1 ? bbase[(uint32_t)key1] : make_float4(-8.f, -8.f, -8.f, -8.f);
        const float  al = box_area(box_lo);
        const float  ah = box_area(box_hi);

        // P1: cross-test vs prior winners, 4 helpers per box (pipelined, no early exit)
        {
            const int bx = t >> 2, q = t & 3;
            const uint64_t keyx = skeys[cb + bx];
            const bool valid = (keyx != ~0ull);
            const float4 bv = valid ? bbase[(uint32_t)keyx] : make_float4(-8.f, -8.f, -8.f, -8.f);
            const float  av = box_area(bv);
            int dead = valid ? 0 : 1;
            #pragma unroll 4
            for (int i = q; i < W; i += 4) {
                dead |= iou_gt(swbox[i], swarea[i], bv, av) ? 1 : 0;
            }
            dead |= __shfl_xor(dead, 1, 64);
            dead |= __shfl_xor(dead, 2, 64);
            if (q == 0) sdead[bx] = (unsigned char)dead;
        }
        __syncthreads();

        // P2: sparse alive-row kill-matrix build; wave w owns rows [16w,16w+16)
        {
            const int rbase = w * 16;
            uint32_t rm = (uint32_t)__ballot(l < 16 && !sdead[rbase + l]) & 0xFFFFu;
            while (rm) {                          // uniform per wave (ballot result)
                const int j = __ffs(rm) - 1; rm &= rm - 1;
                const int row = rbase + j;
                const float4 rowsrc = (row < 64) ? box_lo : box_hi;
                const float4 rbx = shfl_box(rowsrc, row & 63);
                const float  ra  = box_area(rbx);
                const uint64_t m0 = __ballot(iou_gt(rbx, ra, box_lo, al));
                const uint64_t m1 = __ballot(iou_gt(rbx, ra, box_hi, ah));
                if (l == 0) { srow[row][0] = m0; srow[row][1] = m1; }
            }
        }
        __syncthreads();

        // P3: wave-0 scalar resolve: ctz + readlane + andn per winner (R8-verified)
        if (w == 0) {
            const uint64_t r0lo = srow[l][0];        // row l
            const uint64_t r0hi = srow[l][1];
            const uint64_t r1lo = srow[64 + l][0];   // row 64+l
            const uint64_t r1hi = srow[64 + l][1];
            uint64_t alive0 = __ballot(sdead[l] == 0);
            uint64_t alive1 = __ballot(sdead[64 + l] == 0);
            int Wl = W;
            while ((alive0 | alive1) && Wl < TOPK) {
                const int f = alive0 ? __builtin_ctzll(alive0)
                                     : 64 + __builtin_ctzll(alive1);
                if (f < 64) {
                    if (l == f)      { swkey[Wl] = key0; swbox[Wl] = box_lo; swarea[Wl] = al; }
                } else {
                    if (l == f - 64) { swkey[Wl] = key1; swbox[Wl] = box_hi; swarea[Wl] = ah; }
                }
                uint64_t klo, khi;
                if (f < 64) { klo = readlane_u64(r0lo, f);      khi = readlane_u64(r0hi, f); }
                else        { klo = readlane_u64(r1lo, f - 64); khi = readlane_u64(r1hi, f - 64); }
                alive0 &= ~klo;                  // winner self-clears (diag IoU = 1)
                alive1 &= ~khi;
                ++Wl;
            }
            if (l == 0) sW = Wl;
        }
        __syncthreads();
        W = sW;
        if (W >= TOPK) break;
    }

    // epilogue: winners already hold their sorted keys; add class base to index
    const uint32_t  base = (uint32_t)(c - 1) * A_N;
    uint64_t* const out  = ws_keys + ((size_t)b * CF + (c - 1)) * TOPK;
    for (int k2 = t; k2 < TOPK; k2 += CTHREADS) {
        if (k2 < W) {
            const uint64_t kk2 = swkey[k2];
            out[k2] = (kk2 & 0xFFFFFFFF00000000ull) | (uint64_t)(base + (uint32_t)kk2);
        } else {
            out[k2] = ~0ull;
        }
    }
}

// ---- mono fallback (R4 kernel, verified) for tiny ws ----
__global__ __launch_bounds__(THREADS)
void nms_mono(const float* __restrict__ locs,
              const float* __restrict__ scores,
              const float* __restrict__ anchors,
              uint64_t* __restrict__ ws_keys)
{
    __shared__ uint64_t      skeys[SORT_N];
    __shared__ float4        sbox[A_N];
    __shared__ float4        schunk[CH];
    __shared__ uint64_t      srow[CH][2];
    __shared__ float4        swbox[TOPK];
    __shared__ uint64_t      swkey[TOPK];
    __shared__ unsigned char sdead[CH];
    __shared__ int           sW;

    const int blk = blockIdx.x;
    const int b   = blk / CF;
    const int c   = blk % CF + 1;
    const int t   = threadIdx.x;
    const int l   = t & 63;
    const int w   = t >> 6;

    #pragma unroll
    for (int i = 0; i < A_N / THREADS; ++i) {
        const int a = t + i * THREADS;
        const float4 v = decode_box(((const float4*)locs)[(size_t)b * A_N + a],
                                    ((const float4*)anchors)[a]);
        const float* sp = scores + ((size_t)b * A_N + a) * NC;
        float m = sp[0];
        #pragma unroll
        for (int kq = 1; kq < NC; ++kq) m = fmaxf(m, sp[kq]);
        float sum = 0.0f;
        #pragma unroll
        for (int kq = 0; kq < NC; ++kq) sum += expf(sp[kq] - m);
        sbox[a] = v;
        const float sc = expf(sp[c] - m) / sum;
        skeys[a] = (sc > 0.01f) ? pack_key(sc, (uint32_t)a) : ~0ull;
    }
    for (int i = A_N + t; i < SORT_N; i += THREADS) skeys[i] = ~0ull;
    if (t == 0) sW = 0;
    __syncthreads();

    uint64_t k[8];
    #pragma unroll
    for (int r = 0; r < 8; ++r) k[r] = skeys[(w << 9) + (r << 6) + l];
    for (int kk = 2; kk <= SORT_N; kk <<= 1) {
        for (int j = kk >> 1; j; j >>= 1) {
            if (j >= 512) {
                __syncthreads();
                #pragma unroll
                for (int r = 0; r < 8; ++r) skeys[(w << 9) + (r << 6) + l] = k[r];
                __syncthreads();
                #pragma unroll
                for (int r = 0; r < 8; ++r) {
                    const int e = (w << 9) + (r << 6) + l;
                    const uint64_t o = skeys[e ^ j];
                    const bool keep_min = (((e & j) == 0) == ((e & kk) == 0));
                    const uint64_t mn = k[r] < o ? k[r] : o;
                    const uint64_t mx = k[r] < o ? o : k[r];
                    k[r] = keep_min ? mn : mx;
                }
            } else if (j >= 64) {
                const int rb = j >> 6;
                #pragma unroll
                for (int r = 0; r < 8; ++r) {
                    if ((r & rb) == 0) {
                        const int p = r | rb;
                        const int e = (w << 9) + (r << 6) + l;
                        const bool up = ((e & kk) == 0);
                        const uint64_t x = k[r], y = k[p];
                        const uint64_t mn = x < y ? x : y;
                        const uint64_t mx = x < y ? y : x;
                        k[r] = up ? mn : mx;
                        k[p] = up ? mx : mn;
                    }
                }
            } else {
                #pragma unroll
                for (int r = 0; r < 8; ++r) {
                    const uint64_t o = (uint64_t)__shfl_xor((unsigned long long)k[r], j, 64);
                    const int e = (w << 9) + (r << 6) + l;
                    const bool keep_min = (((e & j) == 0) == ((e & kk) == 0));
                    const uint64_t mn = k[r] < o ? k[r] : o;
                    const uint64_t mx = k[r] < o ? o : k[r];
                    k[r] = keep_min ? mn : mx;
                }
            }
        }
    }
    __syncthreads();
    #pragma unroll
    for (int r = 0; r < 8; ++r) skeys[(w << 9) + (r << 6) + l] = k[r];
    __syncthreads();

    int W = 0;
    for (int cb = 0; cb < SORT_N; cb += CH) {
        if (skeys[cb] == ~0ull) break;
        if (t < CH) {
            const uint64_t kc = skeys[cb + t];
            const bool v = (kc != ~0ull);
            schunk[t] = v ? sbox[(uint32_t)kc] : make_float4(-8.f, -8.f, -8.f, -8.f);
            sdead[t]  = v ? 0 : 1;
        }
        __syncthreads();
        const float4 cb0 = schunk[l];
        const float4 cb1 = schunk[64 + l];
        const float  ca0 = box_area(cb0);
        const float  ca1 = box_area(cb1);
        for (int r = w * 32; r < w * 32 + 32; ++r) {
            const float4 rbx = schunk[r];
            const float  ra  = box_area(rbx);
            const uint64_t m0 = __ballot(iou_gt(rbx, ra, cb0, ca0));
            const uint64_t m1 = __ballot(iou_gt(rbx, ra, cb1, ca1));
            if (l == 0) { srow[r][0] = m0; srow[r][1] = m1; }
        }
        {
            const int jj = t >> 1, h = t & 1;
            const float4 bj = schunk[jj];
            const float  aj = box_area(bj);
            int sup = 0;
            for (int w2 = h; w2 < W; w2 += 2) {
                const float4 bw = swbox[w2];
                if (iou_gt(bw, box_area(bw), bj, aj)) { sup = 1; break; }
            }
            sup |= __shfl_xor(sup, 1, 64);
            if (h == 0 && sup) sdead[jj] = 1;
        }
        __syncthreads();
        if (t < 64) {
            bool al0 = !sdead[t];
            bool al1 = !sdead[64 + t];
            int Wl = W;
            while (true) {
                const unsigned long long bal0 = __ballot(al0);
                const unsigned long long bal1 = __ballot(al1);
                if (!(bal0 | bal1)) break;
                const int f = bal0 ? (__ffsll(bal0) - 1) : (64 + __ffsll(bal1) - 1);
                if (t == 0) { swkey[Wl] = skeys[cb + f]; swbox[Wl] = schunk[f]; }
                const uint64_t r0 = srow[f][0];
                const uint64_t r1 = srow[f][1];
                al0 = al0 && !((r0 >> t) & 1);
                al1 = al1 && !((r1 >> t) & 1);
                if (++Wl >= TOPK) break;
            }
            if (t == 0) sW = Wl;
        }
        __syncthreads();
        W = sW;
        if (W >= TOPK) break;
    }

    const uint32_t  base = (uint32_t)(c - 1) * A_N;
    uint64_t* const out  = ws_keys + ((size_t)b * CF + (c - 1)) * TOPK;
    for (int kx = t; kx < TOPK; kx += THREADS) {
        if (kx < W) {
            const uint64_t kk2 = swkey[kx];
            out[kx] = (kk2 & 0xFFFFFFFF00000000ull) | (uint64_t)(base + (uint32_t)kk2);
        } else {
            out[kx] = ~0ull;
        }
    }
}

// ---- merge: per batch top-200 of 20 sorted lists (R2..R12-verified) ----
__global__ __launch_bounds__(THREADS)
void merge_kernel(const float* __restrict__ locs,
                  const float* __restrict__ anchors,
                  const uint64_t* __restrict__ ws_keys,
                  float* __restrict__ out)
{
    __shared__ uint64_t Abuf[20][256];
    __shared__ uint64_t Bbuf[10][256];

    const int b = blockIdx.x;
    const int t = threadIdx.x;
    const uint64_t* const in = ws_keys + (size_t)b * CF * TOPK;

    for (int e = t; e < CF * 256; e += THREADS) {
        const int c = e >> 8, i = e & 255;
        Abuf[c][i] = (i < TOPK) ? in[c * TOPK + i] : ~0ull;
    }

    uint64_t (*src)[256] = Abuf;
    uint64_t (*dst)[256] = Bbuf;
    int n = CF;
    while (n > 1) {
        const int  nm    = n >> 1;
        const bool carry = (n & 1) != 0;
        __syncthreads();
        for (int e = t; e < nm * 256; e += THREADS) {
            const int mm = e >> 8, i = e & 255;
            const uint64_t x = src[2 * mm][i];
            const uint64_t y = src[2 * mm + 1][255 - i];
            dst[mm][i] = x < y ? x : y;              // lower-half extraction (bitonic)
        }
        if (carry)
            for (int i = t; i < 256; i += THREADS) dst[nm][i] = src[n - 1][i];
        for (int j = 128; j; j >>= 1) {
            __syncthreads();
            for (int pp = t; pp < nm * 128; pp += THREADS) {
                const int mm = pp >> 7, qq = pp & 127;
                const int i  = ((qq & ~(j - 1)) << 1) | (qq & (j - 1));
                const uint64_t x = dst[mm][i], y = dst[mm][i + j];
                if (y < x) { dst[mm][i] = y; dst[mm][i + j] = x; }
            }
        }
        uint64_t (*tmp)[256] = src; src = dst; dst = tmp;
        n = nm + (carry ? 1 : 0);
    }
    __syncthreads();

    if (t < TOPK) {
        const uint64_t k = src[0][t];
        float* const boxes_out  = out;                           // [B][TOPK][4]
        float* const labels_out = out + (size_t)B_N * TOPK * 4;  // [B][TOPK]
        float* const scores_out = out + (size_t)B_N * TOPK * 5;  // [B][TOPK]
        const size_t s = (size_t)b * TOPK + t;
        if (k == ~0ull) {
            boxes_out[s * 4 + 0] = 0.0f;
            boxes_out[s * 4 + 1] = 0.0f;
            boxes_out[s * 4 + 2] = 0.0f;
            boxes_out[s * 4 + 3] = 0.0f;
            labels_out[s] = 0.0f;
            scores_out[s] = 0.0f;
        } else {
            const uint32_t flat = (uint32_t)k;
            const int cls = flat / A_N;          // 0..19
            const int a   = flat - cls * A_N;
            const float sc = __uint_as_float(~(uint32_t)(k >> 32));
            const float4 v = decode_box(((const float4*)locs)[(size_t)b * A_N + a],
                                        ((const float4*)anchors)[a]);
            boxes_out[s * 4 + 0] = v.x;
            boxes_out[s * 4 + 1] = v.y;
            boxes_out[s * 4 + 2] = v.z;
            boxes_out[s * 4 + 3] = v.w;
            labels_out[s] = (float)(cls + 1);
            scores_out[s] = sc;
        }
    }
}

extern "C" void kernel_launch(void* const* d_in, const int* in_sizes, int n_in,
                              void* d_out, int out_size, void* d_ws, size_t ws_size,
                              hipStream_t stream) {
    const float* locs    = (const float*)d_in[0];
    const float* scores  = (const float*)d_in[1];
    const float* anchors = (const float*)d_in[2];
    uint64_t* ws_keys  = (uint64_t*)d_ws;
    float4*   boxes_ws = (float4*)((char*)d_ws + BOX_OFF);
    float2*   ms_ws    = (float2*)((char*)d_ws + MS_OFF);
    float*    outp     = (float*)d_out;

    if (ws_size >= (size_t)WS_B_BYTES) {
        hipLaunchKernelGGL(prep_kernel, dim3((B_N * A_N + THREADS - 1) / THREADS),
                           dim3(THREADS), 0, stream, locs, scores, anchors, boxes_ws, ms_ws);
        hipLaunchKernelGGL(fused_nms_kernel, dim3(B_N * CF), dim3(CTHREADS), 0, stream,
                           scores, ms_ws, boxes_ws, ws_keys);
    } else {
        hipLaunchKernelGGL(nms_mono, dim3(B_N * CF), dim3(THREADS), 0, stream,
                           locs, scores, anchors, ws_keys);
    }
    hipLaunchKernelGGL(merge_kernel, dim3(B_N), dim3(THREADS), 0, stream,
                       locs, anchors, ws_keys, outp);
}